// Round 3
// baseline (440.842 us; speedup 1.0000x reference)
//
#include <hip/hip_runtime.h>
#include <math.h>

#define NB 16
#define NH 512
#define NW 512
#define NHW (NH * NW)
#define LAM2 0.01f
#define TOLV 0.001f
#define MAXIT 10
#define ROWS 8                  // rows per block strip
#define NCHUNK (NH / ROWS)      // 64 strips per batch
#define NTHREADS 256
#define TOTALBLKS (NB * NCHUNK) // 1024
#define COMP_STRIDE (NB * NCHUNK)

// ws layout:
//   [0 .. 5*NB*NCHUNK) doubles : partial sums, layout [comp][b][strip]
//   PWS_OFF  : 32 floats  : current p
//   ERR_OFF  : 1 float    : current err
//   CNT_OFF  : MAXIT ints : per-iteration completion counters
#define PARTIALS_N (5 * NB * NCHUNK)
#define PWS_OFF (PARTIALS_N * 8)
#define ERR_OFF (PWS_OFF + 32 * 4)
#define CNT_OFF (ERR_OFF + 4)

__device__ __forceinline__ float cubicf(float t) {
    float a = fabsf(t);
    float a2 = a * a;
    float a3 = a2 * a;
    if (a <= 1.0f) return 1.5f * a3 - 2.5f * a2 + 1.0f;
    if (a < 2.0f)  return -0.5f * a3 + 2.5f * a2 - 4.0f * a + 2.0f;
    return 0.0f;
}

// Per-column bicubic weights + clamped tap indices, bit-identical to reference
__device__ __forceinline__ void col_setup(int c, float tx, float* wx, int* xi) {
    float gx = (float)c + tx;
    float fx = floorf(gx);
    int x0 = (int)fx;
    float dx = gx - fx;
    wx[0] = cubicf(dx + 1.0f);
    wx[1] = cubicf(dx);
    wx[2] = cubicf(dx - 1.0f);
    wx[3] = cubicf(dx - 2.0f);
#pragma unroll
    for (int i = 0; i < 4; ++i) xi[i] = min(max(x0 - 1 + i, 0), NW - 1);
}

__global__ __launch_bounds__(64) void gn_init(const float* __restrict__ p_in,
                                              float* __restrict__ pws,
                                              float* __restrict__ errws,
                                              int* __restrict__ counters) {
    int t = threadIdx.x;
    if (t < 2 * NB) pws[t] = p_in[t];
    if (t == 0) errws[0] = 1e10f;
    if (t < MAXIT) counters[t] = 0;
}

// Fused: per-strip reduction + (last block only) global sum, 2x2 solve, p update.
__global__ __launch_bounds__(NTHREADS) void gn_iter(const float* __restrict__ I1,
                                                    const float* __restrict__ I2,
                                                    float* __restrict__ pws,
                                                    double* __restrict__ partials,
                                                    float* __restrict__ errws,
                                                    int* __restrict__ counter,
                                                    float* __restrict__ out,
                                                    int write_out) {
    const int b = blockIdx.y;
    const int strip = blockIdx.x;
    const int tid = threadIdx.x;
    const float tx = pws[2 * b];
    const float ty = pws[2 * b + 1];
    const float* I1b = I1 + (size_t)b * NHW;
    const float* I2b = I2 + (size_t)b * NHW;

    const int cA = 2 * tid;
    const int cB = 2 * tid + 1;
    float wxA[4], wxB[4];
    int xiA[4], xiB[4];
    col_setup(cA, tx, wxA, xiA);
    col_setup(cB, tx, wxB, xiB);

    __shared__ float wyS[ROWS][4];
    __shared__ int   yjS[ROWS][4];
    __shared__ float V[2][NW];

    const int y0row = strip * ROWS;
    if (tid < ROWS) {
        int y = y0row + tid;
        float gy = (float)y + ty;
        float fy = floorf(gy);
        int yy0 = (int)fy;
        float dy = gy - fy;
        wyS[tid][0] = cubicf(dy + 1.0f);
        wyS[tid][1] = cubicf(dy);
        wyS[tid][2] = cubicf(dy - 1.0f);
        wyS[tid][3] = cubicf(dy - 2.0f);
#pragma unroll
        for (int i = 0; i < 4; ++i) yjS[tid][i] = min(max(yy0 - 1 + i, 0), NH - 1);
    }

    // rolling I1 rows (center / up / down for gradients)
    float2 ccCur = *(const float2*)(I1b + (size_t)y0row * NW + cA);
    float2 ccPrev = make_float2(0.0f, 0.0f);
    if (y0row > 0) ccPrev = *(const float2*)(I1b + (size_t)(y0row - 1) * NW + cA);
    __syncthreads();

    double a0 = 0, a1 = 0, a2 = 0, a3 = 0, a4 = 0;

    for (int r = 0; r < ROWS; ++r) {
        const int y = y0row + r;
        float2 ccNext = make_float2(0.0f, 0.0f);
        if (y + 1 <= NH - 1) ccNext = *(const float2*)(I1b + (size_t)(y + 1) * NW + cA);

        const float wy0 = wyS[r][0], wy1 = wyS[r][1], wy2 = wyS[r][2], wy3 = wyS[r][3];
        const float2* r0 = (const float2*)(I2b + (size_t)yjS[r][0] * NW);
        const float2* r1 = (const float2*)(I2b + (size_t)yjS[r][1] * NW);
        const float2* r2 = (const float2*)(I2b + (size_t)yjS[r][2] * NW);
        const float2* r3 = (const float2*)(I2b + (size_t)yjS[r][3] * NW);
        float2 p0 = r0[tid], p1 = r1[tid], p2 = r2[tid], p3 = r3[tid];
        float* Vb = V[r & 1];
        Vb[cA] = wy0 * p0.x + wy1 * p1.x + wy2 * p2.x + wy3 * p3.x;
        Vb[cB] = wy0 * p0.y + wy1 * p1.y + wy2 * p2.y + wy3 * p3.y;

        // gradients from registers + cross-lane (no V dependency; before barrier)
        const float* I1r = I1b + (size_t)y * NW;
        float left = __shfl_up(ccCur.y, 1);
        if ((tid & 63) == 0) left = (tid > 0) ? I1r[cA - 1] : 0.0f;
        float right = __shfl_down(ccCur.x, 1);
        if ((tid & 63) == 63) right = (tid < NTHREADS - 1) ? I1r[cB + 1] : 0.0f;
        float IxA = (cA >= 1) ? 0.5f * (ccCur.y - left) : 0.0f;
        float IxB = (cB <= NW - 2) ? 0.5f * (right - ccCur.x) : 0.0f;
        float IyA = 0.0f, IyB = 0.0f;
        if (y >= 1 && y <= NH - 2) {
            IyA = 0.5f * (ccNext.x - ccPrev.x);
            IyB = 0.5f * (ccNext.y - ccPrev.y);
        }
        __syncthreads();

        float IwA = wxA[0] * Vb[xiA[0]] + wxA[1] * Vb[xiA[1]] +
                    wxA[2] * Vb[xiA[2]] + wxA[3] * Vb[xiA[3]];
        float IwB = wxB[0] * Vb[xiB[0]] + wxB[1] * Vb[xiB[1]] +
                    wxB[2] * Vb[xiB[2]] + wxB[3] * Vb[xiB[3]];

        float DIA = IwA - ccCur.x, DIB = IwB - ccCur.y;
        float rhoA = 1.0f / sqrtf(DIA * DIA + LAM2);
        float rhoB = 1.0f / sqrtf(DIB * DIB + LAM2);
        float drA = DIA * rhoA, drB = DIB * rhoB;

        a0 += (double)(IxA * IxA * rhoA) + (double)(IxB * IxB * rhoB);
        a1 += (double)(IxA * IyA * rhoA) + (double)(IxB * IyB * rhoB);
        a2 += (double)(IyA * IyA * rhoA) + (double)(IyB * IyB * rhoB);
        a3 += (double)(IxA * drA) + (double)(IxB * drB);
        a4 += (double)(IyA * drA) + (double)(IyB * drB);

        ccPrev = ccCur;
        ccCur = ccNext;
        // V double-buffered: writes to this buffer recur only after next barrier
    }

#pragma unroll
    for (int off = 32; off > 0; off >>= 1) {
        a0 += __shfl_down(a0, off);
        a1 += __shfl_down(a1, off);
        a2 += __shfl_down(a2, off);
        a3 += __shfl_down(a3, off);
        a4 += __shfl_down(a4, off);
    }

    __shared__ double wsum[NTHREADS / 64][5];
    int wave = tid >> 6, lane = tid & 63;
    if (lane == 0) {
        wsum[wave][0] = a0; wsum[wave][1] = a1; wsum[wave][2] = a2;
        wsum[wave][3] = a3; wsum[wave][4] = a4;
    }
    __syncthreads();
    if (tid < 5) {
        double s = wsum[0][tid] + wsum[1][tid] + wsum[2][tid] + wsum[3][tid];
        partials[(size_t)tid * COMP_STRIDE + b * NCHUNK + strip] = s;
    }

    // ---- last-block-done: deterministic global reduction + update ----
    __shared__ int sIsLast;
    if (tid == 0) {
        __threadfence();
        int old = atomicAdd(counter, 1);
        sIsLast = (old == TOTALBLKS - 1) ? 1 : 0;
    }
    __syncthreads();
    if (!sIsLast) return;
    __threadfence();

    __shared__ double Hs[NB][5];
    __shared__ float dpf[NB][2];
    __shared__ float pnew[2 * NB];

    if (tid < NB * 5) {
        int bb = tid & 15, comp = tid >> 4;
        const double* src = partials + (size_t)comp * COMP_STRIDE + bb * NCHUNK;
        double s = 0;
        for (int ch = 0; ch < NCHUNK; ++ch) s += src[ch];
        Hs[bb][comp] = s;
    }
    __syncthreads();

    if (tid < NB) {
        double H00 = Hs[tid][0], H01 = Hs[tid][1], H11 = Hs[tid][2];
        double b0 = Hs[tid][3], b1 = Hs[tid][4];
        double inv = 1.0 / (H00 * H11 - H01 * H01);
        double dp0 = ( H11 * b0 - H01 * b1) * inv;
        double dp1 = (-H01 * b0 + H00 * b1) * inv;
        dpf[tid][0] = (float)dp0;
        dpf[tid][1] = (float)dp1;
    }
    __syncthreads();

    float err_old = errws[0];
    bool active = err_old > TOLV;

    if (tid < 2 * NB) {
        float pv = pws[tid];
        if (active) pv -= dpf[tid >> 1][tid & 1];
        pnew[tid] = pv;
        pws[tid] = pv;
    }

    float err_new = err_old;
    if (tid == 0) {
        if (active) {
            double n = 0;
            for (int i = 0; i < NB; ++i) {
                n += (double)dpf[i][0] * (double)dpf[i][0];
                n += (double)dpf[i][1] * (double)dpf[i][1];
            }
            err_new = (float)sqrt(n);
            errws[0] = err_new;
        }
    }
    __syncthreads();
    if (write_out) {
        if (tid < 2 * NB) out[tid] = pnew[tid];
        if (tid == 0) out[2 * NB] = err_new;
    }
}

__global__ __launch_bounds__(NTHREADS) void gn_final(const float* __restrict__ I1,
                                                     const float* __restrict__ I2,
                                                     const float* __restrict__ pws,
                                                     float* __restrict__ out) {
    const int b = blockIdx.y;
    const int strip = blockIdx.x;
    const int tid = threadIdx.x;
    const float tx = pws[2 * b];
    const float ty = pws[2 * b + 1];
    const float* I1b = I1 + (size_t)b * NHW;
    const float* I2b = I2 + (size_t)b * NHW;

    float* DIout = out + 33;
    float* IWout = out + 33 + (size_t)NB * NHW;

    const int cA = 2 * tid;
    const int cB = 2 * tid + 1;
    float wxA[4], wxB[4];
    int xiA[4], xiB[4];
    col_setup(cA, tx, wxA, xiA);
    col_setup(cB, tx, wxB, xiB);

    __shared__ float wyS[ROWS][4];
    __shared__ int   yjS[ROWS][4];
    __shared__ float V[2][NW];

    if (tid < ROWS) {
        int y = strip * ROWS + tid;
        float gy = (float)y + ty;
        float fy = floorf(gy);
        int yy0 = (int)fy;
        float dy = gy - fy;
        wyS[tid][0] = cubicf(dy + 1.0f);
        wyS[tid][1] = cubicf(dy);
        wyS[tid][2] = cubicf(dy - 1.0f);
        wyS[tid][3] = cubicf(dy - 2.0f);
#pragma unroll
        for (int i = 0; i < 4; ++i) yjS[tid][i] = min(max(yy0 - 1 + i, 0), NH - 1);
    }
    __syncthreads();

    for (int r = 0; r < ROWS; ++r) {
        const int y = strip * ROWS + r;
        const float wy0 = wyS[r][0], wy1 = wyS[r][1], wy2 = wyS[r][2], wy3 = wyS[r][3];
        const float2* r0 = (const float2*)(I2b + (size_t)yjS[r][0] * NW);
        const float2* r1 = (const float2*)(I2b + (size_t)yjS[r][1] * NW);
        const float2* r2 = (const float2*)(I2b + (size_t)yjS[r][2] * NW);
        const float2* r3 = (const float2*)(I2b + (size_t)yjS[r][3] * NW);
        float2 p0 = r0[tid], p1 = r1[tid], p2 = r2[tid], p3 = r3[tid];
        float* Vb = V[r & 1];
        Vb[cA] = wy0 * p0.x + wy1 * p1.x + wy2 * p2.x + wy3 * p3.x;
        Vb[cB] = wy0 * p0.y + wy1 * p1.y + wy2 * p2.y + wy3 * p3.y;
        __syncthreads();

        const float* I1r = I1b + (size_t)y * NW;
        float2 cc = *(const float2*)(I1r + cA);

        float IwA = wxA[0] * Vb[xiA[0]] + wxA[1] * Vb[xiA[1]] +
                    wxA[2] * Vb[xiA[2]] + wxA[3] * Vb[xiA[3]];
        float IwB = wxB[0] * Vb[xiB[0]] + wxB[1] * Vb[xiB[1]] +
                    wxB[2] * Vb[xiB[2]] + wxB[3] * Vb[xiB[3]];

        size_t o = (size_t)b * NHW + (size_t)y * NW + cA;
        float2 dv; dv.x = IwA - cc.x; dv.y = IwB - cc.y;
        float2 wv; wv.x = IwA; wv.y = IwB;
        *(float2*)(DIout + o) = dv;
        *(float2*)(IWout + o) = wv;
    }
}

extern "C" void kernel_launch(void* const* d_in, const int* in_sizes, int n_in,
                              void* d_out, int out_size, void* d_ws, size_t ws_size,
                              hipStream_t stream) {
    const float* I1 = (const float*)d_in[0];
    const float* I2 = (const float*)d_in[1];
    const float* p  = (const float*)d_in[2];
    float* out = (float*)d_out;

    double* partials = (double*)d_ws;
    float* pws   = (float*)((char*)d_ws + PWS_OFF);
    float* errws = (float*)((char*)d_ws + ERR_OFF);
    int* counters = (int*)((char*)d_ws + CNT_OFF);

    gn_init<<<1, 64, 0, stream>>>(p, pws, errws, counters);

    dim3 grid(NCHUNK, NB);
    for (int t = 0; t < MAXIT; ++t) {
        gn_iter<<<grid, NTHREADS, 0, stream>>>(I1, I2, pws, partials, errws,
                                               counters + t, out, (t == MAXIT - 1) ? 1 : 0);
    }
    gn_final<<<grid, NTHREADS, 0, stream>>>(I1, I2, pws, out);
}

// Round 4
// 238.550 us; speedup vs baseline: 1.8480x; 1.8480x over previous
//
#include <hip/hip_runtime.h>
#include <math.h>

#define NB 16
#define NH 512
#define NW 512
#define NHW (NH * NW)
#define LAM2 0.01f
#define TOLV 0.001f
#define MAXIT 10
#define ROWS 8                  // rows per block strip
#define NCHUNK (NH / ROWS)      // 64 strips per batch
#define NTHREADS 256
#define COMP_STRIDE (NB * NCHUNK)

// ws layout:
//   [0 .. 5*NB*NCHUNK) doubles : partial sums, layout [comp][b][strip]
//   PWS_OFF : 32 floats : current p
//   ERR_OFF : 1 float   : current err
#define PARTIALS_N (5 * NB * NCHUNK)
#define PWS_OFF (PARTIALS_N * 8)
#define ERR_OFF (PWS_OFF + 32 * 4)

__device__ __forceinline__ float cubicf(float t) {
    float a = fabsf(t);
    float a2 = a * a;
    float a3 = a2 * a;
    if (a <= 1.0f) return 1.5f * a3 - 2.5f * a2 + 1.0f;
    if (a < 2.0f)  return -0.5f * a3 + 2.5f * a2 - 4.0f * a + 2.0f;
    return 0.0f;
}

// Per-column bicubic weights + clamped tap indices, bit-identical to reference
__device__ __forceinline__ void col_setup(int c, float tx, float* wx, int* xi) {
    float gx = (float)c + tx;
    float fx = floorf(gx);
    int x0 = (int)fx;
    float dx = gx - fx;
    wx[0] = cubicf(dx + 1.0f);
    wx[1] = cubicf(dx);
    wx[2] = cubicf(dx - 1.0f);
    wx[3] = cubicf(dx - 2.0f);
#pragma unroll
    for (int i = 0; i < 4; ++i) xi[i] = min(max(x0 - 1 + i, 0), NW - 1);
}

__global__ __launch_bounds__(64) void gn_init(const float* __restrict__ p_in,
                                              float* __restrict__ pws,
                                              float* __restrict__ errws) {
    int t = threadIdx.x;
    if (t < 2 * NB) pws[t] = p_in[t];
    if (t == 0) errws[0] = 1e10f;
}

__global__ __launch_bounds__(NTHREADS) void gn_reduce(const float* __restrict__ I1,
                                                      const float* __restrict__ I2,
                                                      const float* __restrict__ pws,
                                                      double* __restrict__ partials) {
    const int b = blockIdx.y;
    const int strip = blockIdx.x;
    const int tid = threadIdx.x;
    const float tx = pws[2 * b];
    const float ty = pws[2 * b + 1];
    const float* I1b = I1 + (size_t)b * NHW;
    const float* I2b = I2 + (size_t)b * NHW;

    const int cA = 2 * tid;
    const int cB = 2 * tid + 1;
    float wxA[4], wxB[4];
    int xiA[4], xiB[4];
    col_setup(cA, tx, wxA, xiA);
    col_setup(cB, tx, wxB, xiB);

    __shared__ float wyS[ROWS][4];
    __shared__ int   yjS[ROWS][4];
    __shared__ float V[2][NW];

    const int y0row = strip * ROWS;
    if (tid < ROWS) {
        int y = y0row + tid;
        float gy = (float)y + ty;
        float fy = floorf(gy);
        int yy0 = (int)fy;
        float dy = gy - fy;
        wyS[tid][0] = cubicf(dy + 1.0f);
        wyS[tid][1] = cubicf(dy);
        wyS[tid][2] = cubicf(dy - 1.0f);
        wyS[tid][3] = cubicf(dy - 2.0f);
#pragma unroll
        for (int i = 0; i < 4; ++i) yjS[tid][i] = min(max(yy0 - 1 + i, 0), NH - 1);
    }

    // I1 rolling rows (for gradients): prev / cur / staged-next
    float2 ccPrev = make_float2(0.0f, 0.0f);
    if (y0row > 0) ccPrev = *(const float2*)(I1b + (size_t)(y0row - 1) * NW + cA);
    float2 ccCur = *(const float2*)(I1b + (size_t)y0row * NW + cA);
    float2 ccNextP = *(const float2*)(I1b + (size_t)min(y0row + 1, NH - 1) * NW + cA);

    __syncthreads();   // wyS / yjS visible

    // I2 vertical tap window for output row 0 of the strip
    float2 w0 = ((const float2*)(I2b + (size_t)yjS[0][0] * NW))[tid];
    float2 w1 = ((const float2*)(I2b + (size_t)yjS[0][1] * NW))[tid];
    float2 w2 = ((const float2*)(I2b + (size_t)yjS[0][2] * NW))[tid];
    float2 w3p = ((const float2*)(I2b + (size_t)yjS[0][3] * NW))[tid];

    double a0 = 0, a1 = 0, a2 = 0, a3 = 0, a4 = 0;

#pragma unroll
    for (int r = 0; r < ROWS; ++r) {
        const int y = y0row + r;

        // ---- stage next-iteration loads (issue early, consume next iter) ----
        float2 nI2 = make_float2(0.0f, 0.0f);
        if (r + 1 < ROWS)
            nI2 = ((const float2*)(I2b + (size_t)yjS[r + 1][3] * NW))[tid];
        float2 ncc = ((const float2*)(I1b + (size_t)min(y + 2, NH - 1) * NW))[tid];

        // ---- vertical pass (registers ready from previous iteration) ----
        float2 w3 = w3p;
        const float wy0 = wyS[r][0], wy1 = wyS[r][1], wy2 = wyS[r][2], wy3 = wyS[r][3];
        float* Vb = V[r & 1];
        Vb[cA] = wy0 * w0.x + wy1 * w1.x + wy2 * w2.x + wy3 * w3.x;
        Vb[cB] = wy0 * w0.y + wy1 * w1.y + wy2 * w2.y + wy3 * w3.y;

        // ---- I1 gradients from registers + cross-lane (pre-barrier work) ----
        float2 ccNext = ccNextP;
        const float* I1r = I1b + (size_t)y * NW;
        float left = __shfl_up(ccCur.y, 1);
        if ((tid & 63) == 0) left = (tid > 0) ? I1r[cA - 1] : 0.0f;
        float right = __shfl_down(ccCur.x, 1);
        if ((tid & 63) == 63) right = (tid < NTHREADS - 1) ? I1r[cB + 1] : 0.0f;
        float IxA = (cA >= 1) ? 0.5f * (ccCur.y - left) : 0.0f;
        float IxB = (cB <= NW - 2) ? 0.5f * (right - ccCur.x) : 0.0f;
        float IyA = 0.0f, IyB = 0.0f;
        if (y >= 1 && y <= NH - 2) {
            IyA = 0.5f * (ccNext.x - ccPrev.x);
            IyB = 0.5f * (ccNext.y - ccPrev.y);
        }
        __syncthreads();

        // ---- horizontal pass + robust stats ----
        float IwA = wxA[0] * Vb[xiA[0]] + wxA[1] * Vb[xiA[1]] +
                    wxA[2] * Vb[xiA[2]] + wxA[3] * Vb[xiA[3]];
        float IwB = wxB[0] * Vb[xiB[0]] + wxB[1] * Vb[xiB[1]] +
                    wxB[2] * Vb[xiB[2]] + wxB[3] * Vb[xiB[3]];

        float DIA = IwA - ccCur.x, DIB = IwB - ccCur.y;
        float rhoA = 1.0f / sqrtf(DIA * DIA + LAM2);
        float rhoB = 1.0f / sqrtf(DIB * DIB + LAM2);
        float drA = DIA * rhoA, drB = DIB * rhoB;

        a0 += (double)(IxA * IxA * rhoA) + (double)(IxB * IxB * rhoB);
        a1 += (double)(IxA * IyA * rhoA) + (double)(IxB * IyB * rhoB);
        a2 += (double)(IyA * IyA * rhoA) + (double)(IyB * IyB * rhoB);
        a3 += (double)(IxA * drA) + (double)(IxB * drB);
        a4 += (double)(IyA * drA) + (double)(IyB * drB);

        // ---- roll windows ----
        if (r + 1 < ROWS) {
            bool aligned = (yjS[r + 1][0] == yjS[r][1]) &&
                           (yjS[r + 1][1] == yjS[r][2]) &&
                           (yjS[r + 1][2] == yjS[r][3]);
            if (aligned) {
                w0 = w1; w1 = w2; w2 = w3; w3p = nI2;
            } else {  // pathological f32-floor step (≈never); reload window
                w0 = ((const float2*)(I2b + (size_t)yjS[r + 1][0] * NW))[tid];
                w1 = ((const float2*)(I2b + (size_t)yjS[r + 1][1] * NW))[tid];
                w2 = ((const float2*)(I2b + (size_t)yjS[r + 1][2] * NW))[tid];
                w3p = ((const float2*)(I2b + (size_t)yjS[r + 1][3] * NW))[tid];
            }
        }
        ccPrev = ccCur; ccCur = ccNext; ccNextP = ncc;
        // V double-buffered: this buffer is rewritten only after the next barrier
    }

#pragma unroll
    for (int off = 32; off > 0; off >>= 1) {
        a0 += __shfl_down(a0, off);
        a1 += __shfl_down(a1, off);
        a2 += __shfl_down(a2, off);
        a3 += __shfl_down(a3, off);
        a4 += __shfl_down(a4, off);
    }

    __shared__ double wsum[NTHREADS / 64][5];
    int wave = tid >> 6, lane = tid & 63;
    if (lane == 0) {
        wsum[wave][0] = a0; wsum[wave][1] = a1; wsum[wave][2] = a2;
        wsum[wave][3] = a3; wsum[wave][4] = a4;
    }
    __syncthreads();
    if (tid < 5) {
        double s = wsum[0][tid] + wsum[1][tid] + wsum[2][tid] + wsum[3][tid];
        partials[(size_t)tid * COMP_STRIDE + b * NCHUNK + strip] = s;
    }
}

__global__ __launch_bounds__(128) void gn_update(const double* __restrict__ partials,
                                                 float* __restrict__ pws,
                                                 float* __restrict__ errws,
                                                 float* __restrict__ out,
                                                 int write_out) {
    __shared__ double Hs[NB][5];
    __shared__ float dpf[NB][2];
    __shared__ float pnew[2 * NB];
    const int tid = threadIdx.x;

    if (tid < NB * 5) {
        int bb = tid & 15, comp = tid >> 4;
        const double* src = partials + (size_t)comp * COMP_STRIDE + bb * NCHUNK;
        double s = 0;
#pragma unroll 8
        for (int ch = 0; ch < NCHUNK; ++ch) s += src[ch];
        Hs[bb][comp] = s;
    }
    __syncthreads();

    if (tid < NB) {
        double H00 = Hs[tid][0], H01 = Hs[tid][1], H11 = Hs[tid][2];
        double b0 = Hs[tid][3], b1 = Hs[tid][4];
        double inv = 1.0 / (H00 * H11 - H01 * H01);
        double dp0 = ( H11 * b0 - H01 * b1) * inv;
        double dp1 = (-H01 * b0 + H00 * b1) * inv;
        dpf[tid][0] = (float)dp0;
        dpf[tid][1] = (float)dp1;
    }
    __syncthreads();

    float err_old = errws[0];
    bool active = err_old > TOLV;

    if (tid < 2 * NB) {
        float pv = pws[tid];
        if (active) pv -= dpf[tid >> 1][tid & 1];
        pnew[tid] = pv;
        pws[tid] = pv;
    }

    float err_new = err_old;
    if (tid == 0) {
        if (active) {
            double n = 0;
            for (int i = 0; i < NB; ++i) {
                n += (double)dpf[i][0] * (double)dpf[i][0];
                n += (double)dpf[i][1] * (double)dpf[i][1];
            }
            err_new = (float)sqrt(n);
            errws[0] = err_new;
        }
    }
    __syncthreads();
    if (write_out) {
        if (tid < 2 * NB) out[tid] = pnew[tid];
        if (tid == 0) out[2 * NB] = err_new;
    }
}

__global__ __launch_bounds__(NTHREADS) void gn_final(const float* __restrict__ I1,
                                                     const float* __restrict__ I2,
                                                     const float* __restrict__ pws,
                                                     float* __restrict__ out) {
    const int b = blockIdx.y;
    const int strip = blockIdx.x;
    const int tid = threadIdx.x;
    const float tx = pws[2 * b];
    const float ty = pws[2 * b + 1];
    const float* I1b = I1 + (size_t)b * NHW;
    const float* I2b = I2 + (size_t)b * NHW;

    float* DIout = out + 33;
    float* IWout = out + 33 + (size_t)NB * NHW;

    const int cA = 2 * tid;
    const int cB = 2 * tid + 1;
    float wxA[4], wxB[4];
    int xiA[4], xiB[4];
    col_setup(cA, tx, wxA, xiA);
    col_setup(cB, tx, wxB, xiB);

    __shared__ float wyS[ROWS][4];
    __shared__ int   yjS[ROWS][4];
    __shared__ float V[2][NW];

    const int y0row = strip * ROWS;
    if (tid < ROWS) {
        int y = y0row + tid;
        float gy = (float)y + ty;
        float fy = floorf(gy);
        int yy0 = (int)fy;
        float dy = gy - fy;
        wyS[tid][0] = cubicf(dy + 1.0f);
        wyS[tid][1] = cubicf(dy);
        wyS[tid][2] = cubicf(dy - 1.0f);
        wyS[tid][3] = cubicf(dy - 2.0f);
#pragma unroll
        for (int i = 0; i < 4; ++i) yjS[tid][i] = min(max(yy0 - 1 + i, 0), NH - 1);
    }

    float2 ccP = *(const float2*)(I1b + (size_t)y0row * NW + cA);

    __syncthreads();

    float2 w0 = ((const float2*)(I2b + (size_t)yjS[0][0] * NW))[tid];
    float2 w1 = ((const float2*)(I2b + (size_t)yjS[0][1] * NW))[tid];
    float2 w2 = ((const float2*)(I2b + (size_t)yjS[0][2] * NW))[tid];
    float2 w3p = ((const float2*)(I2b + (size_t)yjS[0][3] * NW))[tid];

#pragma unroll
    for (int r = 0; r < ROWS; ++r) {
        const int y = y0row + r;

        float2 nI2 = make_float2(0.0f, 0.0f);
        if (r + 1 < ROWS)
            nI2 = ((const float2*)(I2b + (size_t)yjS[r + 1][3] * NW))[tid];
        float2 ncc = make_float2(0.0f, 0.0f);
        if (r + 1 < ROWS)
            ncc = *(const float2*)(I1b + (size_t)(y + 1) * NW + cA);

        float2 w3 = w3p;
        const float wy0 = wyS[r][0], wy1 = wyS[r][1], wy2 = wyS[r][2], wy3 = wyS[r][3];
        float* Vb = V[r & 1];
        Vb[cA] = wy0 * w0.x + wy1 * w1.x + wy2 * w2.x + wy3 * w3.x;
        Vb[cB] = wy0 * w0.y + wy1 * w1.y + wy2 * w2.y + wy3 * w3.y;

        float2 cc = ccP;
        __syncthreads();

        float IwA = wxA[0] * Vb[xiA[0]] + wxA[1] * Vb[xiA[1]] +
                    wxA[2] * Vb[xiA[2]] + wxA[3] * Vb[xiA[3]];
        float IwB = wxB[0] * Vb[xiB[0]] + wxB[1] * Vb[xiB[1]] +
                    wxB[2] * Vb[xiB[2]] + wxB[3] * Vb[xiB[3]];

        size_t o = (size_t)b * NHW + (size_t)y * NW + cA;
        float2 dv; dv.x = IwA - cc.x; dv.y = IwB - cc.y;
        float2 wv; wv.x = IwA; wv.y = IwB;
        *(float2*)(DIout + o) = dv;
        *(float2*)(IWout + o) = wv;

        if (r + 1 < ROWS) {
            bool aligned = (yjS[r + 1][0] == yjS[r][1]) &&
                           (yjS[r + 1][1] == yjS[r][2]) &&
                           (yjS[r + 1][2] == yjS[r][3]);
            if (aligned) {
                w0 = w1; w1 = w2; w2 = w3; w3p = nI2;
            } else {
                w0 = ((const float2*)(I2b + (size_t)yjS[r + 1][0] * NW))[tid];
                w1 = ((const float2*)(I2b + (size_t)yjS[r + 1][1] * NW))[tid];
                w2 = ((const float2*)(I2b + (size_t)yjS[r + 1][2] * NW))[tid];
                w3p = ((const float2*)(I2b + (size_t)yjS[r + 1][3] * NW))[tid];
            }
        }
        ccP = ncc;
    }
}

extern "C" void kernel_launch(void* const* d_in, const int* in_sizes, int n_in,
                              void* d_out, int out_size, void* d_ws, size_t ws_size,
                              hipStream_t stream) {
    const float* I1 = (const float*)d_in[0];
    const float* I2 = (const float*)d_in[1];
    const float* p  = (const float*)d_in[2];
    float* out = (float*)d_out;

    double* partials = (double*)d_ws;
    float* pws   = (float*)((char*)d_ws + PWS_OFF);
    float* errws = (float*)((char*)d_ws + ERR_OFF);

    gn_init<<<1, 64, 0, stream>>>(p, pws, errws);

    dim3 grid(NCHUNK, NB);
    for (int t = 0; t < MAXIT; ++t) {
        gn_reduce<<<grid, NTHREADS, 0, stream>>>(I1, I2, pws, partials);
        gn_update<<<1, 128, 0, stream>>>(partials, pws, errws, out, (t == MAXIT - 1) ? 1 : 0);
    }
    gn_final<<<grid, NTHREADS, 0, stream>>>(I1, I2, pws, out);
}